// Round 6
// baseline (492.677 us; speedup 1.0000x reference)
//
#include <hip/hip_runtime.h>

// Problem constants (fixed by reference)
#define R_   3
#define N_   50000
#define E_   400000
#define IN_  128
#define HID_ 64
#define C_   40
#define H_   3
#define NEG_SLOPE 0.2f
#define LOG2E 1.4426950408889634f

#define SCAN_CHUNK 1024
#define NCH  49      // ceil(N_/1024)
#define NCH2 64      // padded stride

#define MPAD 50048   // 782*64 rows (grid-rounded)
#define NRT  3128    // MPAD/16 fragment row-tiles

typedef _Float16 half_t;
typedef _Float16 f16x8 __attribute__((ext_vector_type(8)));
typedef _Float16 f16x4 __attribute__((ext_vector_type(4)));
typedef float float4v __attribute__((ext_vector_type(4)));

template <int V> struct vecT;
template <> struct vecT<4> { typedef f16x4 type; };
template <> struct vecT<8> { typedef f16x8 type; };

// ---------------- merged prep kernel (includes hist) ----------------
// block ranges:
//   [0, 3128)       cast_tiled: feat fp32 -> fragment-tiled fp16 A'
//   [3128, 3164)    bprep<128,3>: W1 -> B1f
//   [3164, 3176)    bprep<64,2>:  W2 -> B2f
//   [3176, 3188)    zero h1T pad row-tiles (3072 halves)
//   [3188]          zero csr tail pad (16 ints past 3E; agg overreads land here)
//   [3189, 4361)    hist: deg atomics (deg pre-zeroed via hipMemsetAsync)

template <int K, int NY>
__device__ inline void bprep_body(int idx, const float* __restrict__ W,
                                  half_t* __restrict__ Bf, int Nc) {
    constexpr int KB = K / 32;
    const int TOT = R_ * NY * KB * 4 * 64;
    if (idx >= TOT) return;
    int lane = idx & 63;
    int ct = (idx >> 6) & 3;
    int t = idx >> 8;                 // (r*NY + y)*KB + kb
    int kb = t % KB; t /= KB;
    int y = t % NY;  int r = t / NY;
    int col = y * 64 + ct * 16 + (lane & 15);
    int k0 = kb * 32 + (lane >> 4) * 8;
    f16x8 h = {};
    if (col < Nc) {
        #pragma unroll
        for (int j = 0; j < 8; ++j)
            h[j] = (half_t)W[((size_t)r * K + k0 + j) * Nc + col];
    }
    ((f16x8*)Bf)[idx] = h;
}

__global__ void prep_kernel(const float* __restrict__ feat, half_t* __restrict__ At,
                            const float* __restrict__ W1, half_t* __restrict__ B1f,
                            const float* __restrict__ W2, half_t* __restrict__ B2f,
                            half_t* __restrict__ h1T, int* __restrict__ csr_src,
                            const int* __restrict__ dst, int* __restrict__ deg) {
    int b = blockIdx.x;
    if (b < 3128) {
        int idx = b * 256 + threadIdx.x;
        int lane = idx & 63;
        int kb = (idx >> 6) & 3;
        int rowtile = idx >> 8;
        int row = rowtile * 16 + (lane & 15);
        int k = kb * 32 + (lane >> 4) * 8;
        f16x8 h = {};
        if (row < N_) {
            const float* p = feat + (size_t)row * IN_ + k;
            float4 a = ((const float4*)p)[0];
            float4 c = ((const float4*)p)[1];
            h[0] = (half_t)a.x; h[1] = (half_t)a.y; h[2] = (half_t)a.z; h[3] = (half_t)a.w;
            h[4] = (half_t)c.x; h[5] = (half_t)c.y; h[6] = (half_t)c.z; h[7] = (half_t)c.w;
        }
        ((f16x8*)At)[idx] = h;
    } else if (b < 3164) {
        bprep_body<IN_, 3>((b - 3128) * 256 + threadIdx.x, W1, B1f, H_ * HID_);
    } else if (b < 3176) {
        bprep_body<HID_, 2>((b - 3164) * 256 + threadIdx.x, W2, B2f, H_ * C_);
    } else if (b < 3188) {
        int i = (b - 3176) * 256 + threadIdx.x;
        if (i < 3072) h1T[(size_t)3125 * 2 * 512 + i] = (half_t)0.f;
    } else if (b == 3188) {
        if (threadIdx.x < 16) csr_src[(size_t)R_ * E_ + threadIdx.x] = 0;
    } else {
        // hist: 4 edges per thread -> 4 independent atomic chains in flight
        const int T = (R_ * E_) / 4;
        int t = (b - 3189) * 256 + threadIdx.x;
        if (t < T) {
            #pragma unroll
            for (int j = 0; j < 4; ++j) {
                int idx = t + j * T;
                int r = idx / E_;
                atomicAdd(&deg[r * N_ + dst[idx]], 1);
            }
        }
    }
}

// ---------------- CSR build ----------------
__global__ void scanA_kernel(const int* __restrict__ deg, int* __restrict__ bsum) {
    int r = blockIdx.y, ch = blockIdx.x, tid = threadIdx.x;
    int base = ch * SCAN_CHUNK + tid * 4;
    int s = 0;
    for (int j = 0; j < 4; ++j) {
        int i = base + j;
        if (i < N_) s += deg[r * N_ + i];
    }
    __shared__ int red[256];
    red[tid] = s; __syncthreads();
    for (int off = 128; off; off >>= 1) {
        if (tid < off) red[tid] += red[tid + off];
        __syncthreads();
    }
    if (tid == 0) bsum[r * NCH2 + ch] = red[0];
}

// scanC: folds the 49-element chunk-prefix into each block (wave 0 re-scans).
__global__ void scanC_kernel(const int* __restrict__ deg, const int* __restrict__ bsum,
                             int* __restrict__ rowptr, int* __restrict__ cursor) {
    int r = blockIdx.y, ch = blockIdx.x, tid = threadIdx.x;
    __shared__ int chbase_s;
    if (tid < 64) {
        int v = (tid < NCH) ? bsum[r * NCH2 + tid] : 0;
        int s = v;
        #pragma unroll
        for (int off = 1; off < 64; off <<= 1) {
            int t = __shfl_up(s, off);
            if (tid >= off) s += t;
        }
        if (tid == ch) chbase_s = s - v;   // exclusive prefix of chunk ch
    }
    int base = ch * SCAN_CHUNK + tid * 4;
    int v[4]; int s = 0;
    for (int j = 0; j < 4; ++j) {
        int i = base + j;
        v[j] = (i < N_) ? deg[r * N_ + i] : 0;
        s += v[j];
    }
    __shared__ int buf[256];
    buf[tid] = s; __syncthreads();
    for (int off = 1; off < 256; off <<= 1) {
        int t2 = (tid >= off) ? buf[tid - off] : 0;
        __syncthreads();
        buf[tid] += t2;
        __syncthreads();
    }
    int excl = buf[tid] - s + chbase_s;
    int run = excl;
    for (int j = 0; j < 4; ++j) {
        int i = base + j;
        if (i < N_) {
            rowptr[r * (N_ + 1) + i] = run;
            cursor[r * N_ + i] = run;
            run += v[j];
        }
    }
    if (ch == 0 && tid == 0) rowptr[r * (N_ + 1) + N_] = E_;
}

// fill: store src*3 ("s3"); 4 edges/thread for atomic MLP; single store stream.
__global__ void fill_kernel(const int* __restrict__ src, const int* __restrict__ dst,
                            int* __restrict__ cursor, int* __restrict__ csr_src) {
    const int T = (R_ * E_) / 4;
    int t = blockIdx.x * 256 + threadIdx.x;
    if (t >= T) return;
    int pos[4], s3[4], rr[4];
    #pragma unroll
    for (int j = 0; j < 4; ++j) {
        int idx = t + j * T;
        rr[j] = idx / E_;
        pos[j] = atomicAdd(&cursor[rr[j] * N_ + dst[idx]], 1);
        s3[j] = src[idx] * 3;
    }
    #pragma unroll
    for (int j = 0; j < 4; ++j)
        csr_src[(size_t)rr[j] * E_ + pos[j]] = s3[j];
}

// ---------------- MFMA GEMM v3: fragment-ordered operands ----------------
template <int K, int NY, bool FUSE>
__global__ __launch_bounds__(256) void mfma_gemm3_kernel(
        const half_t* __restrict__ At, const half_t* __restrict__ Bf,
        half_t* __restrict__ Z, int Nc,
        const float* __restrict__ al, const float* __restrict__ ar,
        float* __restrict__ el, float* __restrict__ er) {
    constexpr int KB = K / 32;
    int r = blockIdx.z, y = blockIdx.y;
    int wave = threadIdx.x >> 6, lane = threadIdx.x & 63;
    int rowtile = blockIdx.x * 4 + wave;
    const f16x8* Ap = (const f16x8*)At + (size_t)rowtile * KB * 64 + lane;
    const f16x8* Bp = (const f16x8*)Bf + (size_t)(r * NY + y) * KB * 4 * 64 + lane;
    float4v acc[4] = {};
    #pragma unroll
    for (int kb = 0; kb < KB; ++kb) {
        f16x8 af = Ap[kb * 64];
        #pragma unroll
        for (int ct = 0; ct < 4; ++ct) {
            f16x8 bf = Bp[(kb * 4 + ct) * 64];
            acc[ct] = __builtin_amdgcn_mfma_f32_16x16x32_f16(af, bf, acc[ct], 0, 0, 0);
        }
    }
    int lrow = lane & 15, lq = lane >> 4;
    half_t* Zr = Z + (size_t)r * N_ * Nc;
    int rbase = rowtile * 16 + lq * 4;
    int col0 = y * 64;
    float elv[4] = {}, erv[4] = {};
    const float* alp;
    const float* arp;
    if constexpr (FUSE) {
        alp = al + ((size_t)r * H_ + y) * 64;
        arp = ar + ((size_t)r * H_ + y) * 64;
    }
    #pragma unroll
    for (int ct = 0; ct < 4; ++ct) {
        int col = col0 + ct * 16 + lrow;
        if (col >= Nc) continue;
        float wa = 0.f, wb = 0.f;
        if constexpr (FUSE) { wa = alp[ct * 16 + lrow]; wb = arp[ct * 16 + lrow]; }
        #pragma unroll
        for (int g = 0; g < 4; ++g) {
            int row = rbase + g;
            half_t zh = (half_t)acc[ct][g];
            if (row < N_) Zr[(size_t)row * Nc + col] = zh;
            if constexpr (FUSE) {
                float zf = (float)zh;
                elv[g] = fmaf(zf, wa, elv[g]);
                erv[g] = fmaf(zf, wb, erv[g]);
            }
        }
    }
    if constexpr (FUSE) {
        #pragma unroll
        for (int g = 0; g < 4; ++g) {
            #pragma unroll
            for (int m = 1; m < 16; m <<= 1) {
                elv[g] += __shfl_xor(elv[g], m);
                erv[g] += __shfl_xor(erv[g], m);
            }
        }
        if (lrow == 0) {
            #pragma unroll
            for (int g = 0; g < 4; ++g) {
                int row = rbase + g;
                if (row < N_) {
                    size_t o = ((size_t)r * N_ + row) * H_ + y;
                    el[o] = elv[g] * LOG2E;
                    er[o] = erv[g] * LOG2E;
                }
            }
        }
    }
}

// ---------------- attention logits (layer 2 only) ----------------
template <int Dd>
__global__ __launch_bounds__(256) void attn2_kernel(
        const half_t* __restrict__ z, const float* __restrict__ al,
        const float* __restrict__ ar, float* __restrict__ el,
        float* __restrict__ er) {
    int t = blockIdx.x * 256 + threadIdx.x;
    if (t >= R_ * N_ * H_) return;
    int rn = t / H_, h = t - rn * H_;
    int r = rn / N_;
    const half_t* zrow = z + (size_t)rn * (3 * Dd) + h * Dd;
    const float* alp = al + (r * H_ + h) * Dd;
    const float* arp = ar + (r * H_ + h) * Dd;
    float p0 = 0.f, p1 = 0.f, q0 = 0.f, q1 = 0.f;
    #pragma unroll
    for (int c = 0; c < Dd / 8; ++c) {
        f16x8 zv = *(const f16x8*)(zrow + c * 8);
        #pragma unroll
        for (int j = 0; j < 8; j += 2) {
            float za = (float)zv[j], zb = (float)zv[j + 1];
            p0 += za * alp[c * 8 + j];
            p1 += zb * alp[c * 8 + j + 1];
            q0 += za * arp[c * 8 + j];
            q1 += zb * arp[c * 8 + j + 1];
        }
    }
    el[t] = (p0 + p1) * LOG2E;
    er[t] = (q0 + q1) * LOG2E;
}

// ---------------- split-relation softmax-aggregate (v17) ----------------
// agg14's merged loop ran ceil(max_r deg_r/4) iterations executing all 3
// relation bodies every time: 62% slot efficiency at Poisson(8). Split:
// block = (64,3,2) = 2 nodes x 3 relations, one WAVE per (node, relation);
// each wave iterates ceil(deg_r/4) (85% efficiency) -> ~24% fewer VALU
// issues per useful edge. Per-relation gather pattern, exp path, and fp16
// accumulation order are identical to agg14; only the cross-relation sum
// moves to a 1.5KB LDS combine (fp32 reassociation, ~1e-7).
// Guards dropped vs agg14 (both verified in-bounds of d_ws):
//  - cs index clamp: csr tail padded; mid-relation overreads hit the next
//    node's valid edges and are zeroed by the ok-cndmask.
//  - 'act' lane guard: inactive sub-lanes (sub>=LPE) read/accumulate
//    garbage that no epilogue shuffle path ever consumes.
template <int Dd, int VEC, bool RELU, typename OutT, bool TILED>
__global__ __launch_bounds__(384) void agg17_kernel(
        const int* __restrict__ rowptr, const int* __restrict__ csr_src,
        const half_t* __restrict__ z, const float* __restrict__ el,
        const float* __restrict__ er, const float* __restrict__ bias,
        OutT* __restrict__ out, float scale) {
    constexpr int ROWH = 3 * Dd;        // halves per z row
    constexpr int LPE  = ROWH / VEC;    // sub-lanes per edge (24 / 30)
    constexpr int PH   = Dd / VEC;      // sub-lanes per head (8 / 10)
    using fv = typename vecT<VEC>::type;
    int lane = threadIdx.x;             // 0..63
    int r    = threadIdx.y;             // relation 0..2
    int slot = threadIdx.z;             // node slot 0..1
    int n = blockIdx.x * 2 + slot;
    int hf = lane >> 5;                 // half-wave index
    int sub = lane & 31;
    int hl = sub / PH;                  // 0..3 (3 = dead lanes, harmless)
    int dl = sub - hl * PH;
    int zoff = VEC * sub;
    int ii = rowptr[r * (N_ + 1) + n];
    int ee = rowptr[r * (N_ + 1) + n + 1];
    float erv = er[((size_t)r * N_ + n) * H_ + hl];
    const int* cs = csr_src + (size_t)r * E_;
    const half_t* zr = z + (size_t)r * N_ * ROWH;
    const float* elr = el + (size_t)r * N_ * H_;
    fv ah = {};                         // fp16 packed accumulator
    float ll = 0.f;
    for (; ii < ee; ii += 4) {          // wave-uniform trip count
        int eA = ii + hf, eB = ii + 2 + hf;
        bool okA = eA < ee, okB = eB < ee;
        int sA = cs[eA];                // s3 = src*3 (overread-safe)
        int sB = cs[eB];
        float xA = elr[sA + hl] + erv;
        float xB = elr[sB + hl] + erv;
        fv zA = *(const fv*)(zr + (size_t)sA * Dd + zoff);
        fv zB = *(const fv*)(zr + (size_t)sB * Dd + zoff);
        xA = fmaxf(xA, NEG_SLOPE * xA);
        xB = fmaxf(xB, NEG_SLOPE * xB);
        float cA = okA ? __builtin_amdgcn_exp2f(xA) : 0.f;
        float cB = okB ? __builtin_amdgcn_exp2f(xB) : 0.f;
        ll += cA + cB;
        half_t hA = (half_t)cA, hB = (half_t)cB;
        fv vA, vB;
        #pragma unroll
        for (int v = 0; v < VEC; ++v) { vA[v] = hA; vB[v] = hB; }
        ah += vA * zA + vB * zB;        // v_pk_fma_f16
    }
    // ---- per-relation epilogue (same math as agg14, single r) ----
    float aa[VEC];
    #pragma unroll
    for (int v = 0; v < VEC; ++v) aa[v] = (float)ah[v];
    #pragma unroll
    for (int v = 0; v < VEC; ++v) aa[v] += __shfl(aa[v], lane ^ 32);
    ll += __shfl(ll, lane ^ 32);
    float li = (ll > 0.f) ? 1.f / ll : 0.f;
    const float* br = bias + r * ROWH + hl * Dd + VEC * dl;
    float vacc[VEC];
    #pragma unroll
    for (int v = 0; v < VEC; ++v) {
        float t = aa[v] * li + br[v];
        if (RELU) t = fmaxf(t, 0.f);
        vacc[v] = t;
    }
    int base = lane & 32;
    int p1 = sub + PH;     if (p1 >= LPE) p1 -= LPE;
    int p2 = sub + 2 * PH; if (p2 >= LPE) p2 -= LPE;
    #pragma unroll
    for (int v = 0; v < VEC; ++v)
        vacc[v] += __shfl(vacc[v], base + p1) + __shfl(vacc[v], base + p2);
    int srcl = lane / VEC;
    int cm = lane & (VEC - 1);
    float tv[VEC];
    #pragma unroll
    for (int v = 0; v < VEC; ++v) tv[v] = __shfl(vacc[v], srcl);
    float outv = tv[0];
    #pragma unroll
    for (int v = 1; v < VEC; ++v) outv = (cm == v) ? tv[v] : outv;
    // ---- cross-relation sum via LDS ----
    __shared__ float red[2][3][64];
    red[slot][r][lane] = outv;
    __syncthreads();
    if (r == 0) {
        float o = (red[slot][0][lane] + red[slot][1][lane] + red[slot][2][lane]) * scale;
        if constexpr (TILED) {
            // lane == k (0..63); write fragment-tiled A' for next layer (KB=2)
            int rowtile = n >> 4;
            int kb = lane >> 5;
            int fl = (n & 15) + ((lane >> 3) & 3) * 16;
            int elo = lane & 7;
            size_t ho = (((size_t)rowtile * 2 + kb) * 64 + fl) * 8 + elo;
            ((half_t*)out)[ho] = (half_t)o;
        } else {
            if (lane < Dd) out[(size_t)n * Dd + lane] = (OutT)o;
        }
    }
}

// ---------------- launch ----------------
static inline size_t align256(size_t x) { return (x + 255) & ~(size_t)255; }

extern "C" void kernel_launch(void* const* d_in, const int* in_sizes, int n_in,
                              void* d_out, int out_size, void* d_ws, size_t ws_size,
                              hipStream_t stream) {
    const float* feat = (const float*)d_in[0];
    const int*   src  = (const int*)d_in[1];
    const int*   dst  = (const int*)d_in[2];
    const float* W1   = (const float*)d_in[3];
    const float* al1  = (const float*)d_in[4];
    const float* ar1  = (const float*)d_in[5];
    const float* b1   = (const float*)d_in[6];
    const float* W2   = (const float*)d_in[7];
    const float* al2  = (const float*)d_in[8];
    const float* ar2  = (const float*)d_in[9];
    const float* b2   = (const float*)d_in[10];
    float* out = (float*)d_out;

    // workspace carve
    char* ws = (char*)d_ws;
    size_t off = 0;
    half_t* zbuf  = (half_t*)(ws + off); off += align256((size_t)R_ * N_ * (3 * HID_) * 2);
    half_t* featT = (half_t*)(ws + off); off += align256((size_t)NRT * 4 * 64 * 8 * 2);
    half_t* h1T   = (half_t*)(ws + off); off += align256((size_t)NRT * 2 * 64 * 8 * 2);
    half_t* B1f   = (half_t*)(ws + off); off += align256((size_t)R_ * 3 * 4 * 4 * 64 * 8 * 2);
    half_t* B2f   = (half_t*)(ws + off); off += align256((size_t)R_ * 2 * 2 * 4 * 64 * 8 * 2);
    float* el   = (float*)(ws + off); off += align256((size_t)R_ * N_ * H_ * 4);
    float* er   = (float*)(ws + off); off += align256((size_t)R_ * N_ * H_ * 4);
    int* deg    = (int*)(ws + off);   off += align256((size_t)R_ * N_ * 4);
    int* rowptr = (int*)(ws + off);   off += align256((size_t)R_ * (N_ + 1) * 4);
    int* cursor = (int*)(ws + off);   off += align256((size_t)R_ * N_ * 4);
    int* bsum   = (int*)(ws + off);   off += align256((size_t)R_ * NCH2 * 4);
    int* csr    = (int*)(ws + off);   off += align256((size_t)R_ * E_ * 4 + 64);
    (void)ws_size; (void)n_in; (void)in_sizes; (void)out_size;

    const int ROW_TILES = (N_ + 63) / 64;              // 782
    const int ATTN_BLOCKS = (R_ * N_ * H_ + 255) / 256;// 1758
    const int E4_BLOCKS = (R_ * E_ / 4 + 255) / 256;   // 1172
    const int PREP_BLOCKS = 3189 + E4_BLOCKS;          // 4361
    const dim3 AGG_BLK(64, 3, 2);                      // 2 nodes x 3 relations
    const int AGG_GRID = N_ / 2;                       // 25000

    // ---- deg zero (stream-ordered, graph-capturable) then merged prep+hist ----
    hipMemsetAsync(deg, 0, (size_t)R_ * N_ * 4, stream);
    prep_kernel<<<PREP_BLOCKS, 256, 0, stream>>>(feat, featT, W1, B1f, W2, B2f,
                                                 h1T, csr, dst, deg);

    // ---- CSR build (shared by both layers) ----
    scanA_kernel<<<dim3(NCH, R_), 256, 0, stream>>>(deg, bsum);
    scanC_kernel<<<dim3(NCH, R_), 256, 0, stream>>>(deg, bsum, rowptr, cursor);
    fill_kernel<<<E4_BLOCKS, 256, 0, stream>>>(src, dst, cursor, csr);

    // ---- layer 1: IN -> H*HID, relu; gemm fuses el/er; agg writes h1T tiled ----
    mfma_gemm3_kernel<IN_, 3, true><<<dim3(ROW_TILES, 3, R_), 256, 0, stream>>>(
        featT, B1f, zbuf, H_ * HID_, al1, ar1, el, er);
    agg17_kernel<HID_, 8, true, half_t, true><<<AGG_GRID, AGG_BLK, 0, stream>>>(
        rowptr, csr, zbuf, el, er, b1, h1T, 1.f / (H_ * R_));

    // ---- layer 2: HID -> H*C, no relu; agg writes d_out (fp32) ----
    mfma_gemm3_kernel<HID_, 2, false><<<dim3(ROW_TILES, 2, R_), 256, 0, stream>>>(
        h1T, B2f, zbuf, H_ * C_, nullptr, nullptr, nullptr, nullptr);
    attn2_kernel<C_><<<ATTN_BLOCKS, 256, 0, stream>>>(zbuf, al2, ar2, el, er);
    agg17_kernel<C_, 4, false, float, false><<<AGG_GRID, AGG_BLK, 0, stream>>>(
        rowptr, csr, zbuf, el, er, b2, out, 1.f / (H_ * R_));
}

// Round 7
// 482.142 us; speedup vs baseline: 1.0219x; 1.0219x over previous
//
#include <hip/hip_runtime.h>

// Problem constants (fixed by reference)
#define R_   3
#define N_   50000
#define E_   400000
#define IN_  128
#define HID_ 64
#define C_   40
#define H_   3
#define NEG_SLOPE 0.2f
#define LOG2E 1.4426950408889634f

#define SCAN_CHUNK 1024
#define NCH  49      // ceil(N_/1024)
#define NCH2 64      // padded stride

#define MPAD 50048   // 782*64 rows (grid-rounded)
#define NRT  3128    // MPAD/16 fragment row-tiles

typedef _Float16 half_t;
typedef _Float16 f16x8 __attribute__((ext_vector_type(8)));
typedef _Float16 f16x4 __attribute__((ext_vector_type(4)));
typedef float float4v __attribute__((ext_vector_type(4)));

template <int V> struct vecT;
template <> struct vecT<4> { typedef f16x4 type; };
template <> struct vecT<8> { typedef f16x8 type; };

// ---------------- merged prep kernel (includes hist) ----------------
// block ranges:
//   [0, 3128)       cast_tiled: feat fp32 -> fragment-tiled fp16 A'
//   [3128, 3164)    bprep<128,3>: W1 -> B1f
//   [3164, 3176)    bprep<64,2>:  W2 -> B2f
//   [3176, 3188)    zero h1T pad row-tiles (3072 halves)
//   [3188]          zero csr tail pad (16 ints past 3E; agg overreads land here)
//   [3189, 4361)    hist: deg atomics (deg pre-zeroed via hipMemsetAsync)

template <int K, int NY>
__device__ inline void bprep_body(int idx, const float* __restrict__ W,
                                  half_t* __restrict__ Bf, int Nc) {
    constexpr int KB = K / 32;
    const int TOT = R_ * NY * KB * 4 * 64;
    if (idx >= TOT) return;
    int lane = idx & 63;
    int ct = (idx >> 6) & 3;
    int t = idx >> 8;                 // (r*NY + y)*KB + kb
    int kb = t % KB; t /= KB;
    int y = t % NY;  int r = t / NY;
    int col = y * 64 + ct * 16 + (lane & 15);
    int k0 = kb * 32 + (lane >> 4) * 8;
    f16x8 h = {};
    if (col < Nc) {
        #pragma unroll
        for (int j = 0; j < 8; ++j)
            h[j] = (half_t)W[((size_t)r * K + k0 + j) * Nc + col];
    }
    ((f16x8*)Bf)[idx] = h;
}

__global__ void prep_kernel(const float* __restrict__ feat, half_t* __restrict__ At,
                            const float* __restrict__ W1, half_t* __restrict__ B1f,
                            const float* __restrict__ W2, half_t* __restrict__ B2f,
                            half_t* __restrict__ h1T, int* __restrict__ csr_src,
                            const int* __restrict__ dst, int* __restrict__ deg) {
    int b = blockIdx.x;
    if (b < 3128) {
        int idx = b * 256 + threadIdx.x;
        int lane = idx & 63;
        int kb = (idx >> 6) & 3;
        int rowtile = idx >> 8;
        int row = rowtile * 16 + (lane & 15);
        int k = kb * 32 + (lane >> 4) * 8;
        f16x8 h = {};
        if (row < N_) {
            const float* p = feat + (size_t)row * IN_ + k;
            float4 a = ((const float4*)p)[0];
            float4 c = ((const float4*)p)[1];
            h[0] = (half_t)a.x; h[1] = (half_t)a.y; h[2] = (half_t)a.z; h[3] = (half_t)a.w;
            h[4] = (half_t)c.x; h[5] = (half_t)c.y; h[6] = (half_t)c.z; h[7] = (half_t)c.w;
        }
        ((f16x8*)At)[idx] = h;
    } else if (b < 3164) {
        bprep_body<IN_, 3>((b - 3128) * 256 + threadIdx.x, W1, B1f, H_ * HID_);
    } else if (b < 3176) {
        bprep_body<HID_, 2>((b - 3164) * 256 + threadIdx.x, W2, B2f, H_ * C_);
    } else if (b < 3188) {
        int i = (b - 3176) * 256 + threadIdx.x;
        if (i < 3072) h1T[(size_t)3125 * 2 * 512 + i] = (half_t)0.f;
    } else if (b == 3188) {
        if (threadIdx.x < 16) csr_src[(size_t)R_ * E_ + threadIdx.x] = 0;
    } else {
        // hist: 4 edges per thread -> 4 independent atomic chains in flight
        const int T = (R_ * E_) / 4;
        int t = (b - 3189) * 256 + threadIdx.x;
        if (t < T) {
            #pragma unroll
            for (int j = 0; j < 4; ++j) {
                int idx = t + j * T;
                int r = idx / E_;
                atomicAdd(&deg[r * N_ + dst[idx]], 1);
            }
        }
    }
}

// ---------------- CSR build ----------------
__global__ void scanA_kernel(const int* __restrict__ deg, int* __restrict__ bsum) {
    int r = blockIdx.y, ch = blockIdx.x, tid = threadIdx.x;
    int base = ch * SCAN_CHUNK + tid * 4;
    int s = 0;
    for (int j = 0; j < 4; ++j) {
        int i = base + j;
        if (i < N_) s += deg[r * N_ + i];
    }
    __shared__ int red[256];
    red[tid] = s; __syncthreads();
    for (int off = 128; off; off >>= 1) {
        if (tid < off) red[tid] += red[tid + off];
        __syncthreads();
    }
    if (tid == 0) bsum[r * NCH2 + ch] = red[0];
}

// scanC: folds the 49-element chunk-prefix into each block (wave 0 re-scans).
__global__ void scanC_kernel(const int* __restrict__ deg, const int* __restrict__ bsum,
                             int* __restrict__ rowptr, int* __restrict__ cursor) {
    int r = blockIdx.y, ch = blockIdx.x, tid = threadIdx.x;
    __shared__ int chbase_s;
    if (tid < 64) {
        int v = (tid < NCH) ? bsum[r * NCH2 + tid] : 0;
        int s = v;
        #pragma unroll
        for (int off = 1; off < 64; off <<= 1) {
            int t = __shfl_up(s, off);
            if (tid >= off) s += t;
        }
        if (tid == ch) chbase_s = s - v;   // exclusive prefix of chunk ch
    }
    int base = ch * SCAN_CHUNK + tid * 4;
    int v[4]; int s = 0;
    for (int j = 0; j < 4; ++j) {
        int i = base + j;
        v[j] = (i < N_) ? deg[r * N_ + i] : 0;
        s += v[j];
    }
    __shared__ int buf[256];
    buf[tid] = s; __syncthreads();
    for (int off = 1; off < 256; off <<= 1) {
        int t2 = (tid >= off) ? buf[tid - off] : 0;
        __syncthreads();
        buf[tid] += t2;
        __syncthreads();
    }
    int excl = buf[tid] - s + chbase_s;
    int run = excl;
    for (int j = 0; j < 4; ++j) {
        int i = base + j;
        if (i < N_) {
            rowptr[r * (N_ + 1) + i] = run;
            cursor[r * N_ + i] = run;
            run += v[j];
        }
    }
    if (ch == 0 && tid == 0) rowptr[r * (N_ + 1) + N_] = E_;
}

// fill: store src*3 ("s3"); 4 edges/thread for atomic MLP; single store stream.
__global__ void fill_kernel(const int* __restrict__ src, const int* __restrict__ dst,
                            int* __restrict__ cursor, int* __restrict__ csr_src) {
    const int T = (R_ * E_) / 4;
    int t = blockIdx.x * 256 + threadIdx.x;
    if (t >= T) return;
    int pos[4], s3[4], rr[4];
    #pragma unroll
    for (int j = 0; j < 4; ++j) {
        int idx = t + j * T;
        rr[j] = idx / E_;
        pos[j] = atomicAdd(&cursor[rr[j] * N_ + dst[idx]], 1);
        s3[j] = src[idx] * 3;
    }
    #pragma unroll
    for (int j = 0; j < 4; ++j)
        csr_src[(size_t)rr[j] * E_ + pos[j]] = s3[j];
}

// ---------------- MFMA GEMM v3: fragment-ordered operands ----------------
template <int K, int NY, bool FUSE>
__global__ __launch_bounds__(256) void mfma_gemm3_kernel(
        const half_t* __restrict__ At, const half_t* __restrict__ Bf,
        half_t* __restrict__ Z, int Nc,
        const float* __restrict__ al, const float* __restrict__ ar,
        float* __restrict__ el, float* __restrict__ er) {
    constexpr int KB = K / 32;
    int r = blockIdx.z, y = blockIdx.y;
    int wave = threadIdx.x >> 6, lane = threadIdx.x & 63;
    int rowtile = blockIdx.x * 4 + wave;
    const f16x8* Ap = (const f16x8*)At + (size_t)rowtile * KB * 64 + lane;
    const f16x8* Bp = (const f16x8*)Bf + (size_t)(r * NY + y) * KB * 4 * 64 + lane;
    float4v acc[4] = {};
    #pragma unroll
    for (int kb = 0; kb < KB; ++kb) {
        f16x8 af = Ap[kb * 64];
        #pragma unroll
        for (int ct = 0; ct < 4; ++ct) {
            f16x8 bf = Bp[(kb * 4 + ct) * 64];
            acc[ct] = __builtin_amdgcn_mfma_f32_16x16x32_f16(af, bf, acc[ct], 0, 0, 0);
        }
    }
    int lrow = lane & 15, lq = lane >> 4;
    half_t* Zr = Z + (size_t)r * N_ * Nc;
    int rbase = rowtile * 16 + lq * 4;
    int col0 = y * 64;
    float elv[4] = {}, erv[4] = {};
    const float* alp;
    const float* arp;
    if constexpr (FUSE) {
        alp = al + ((size_t)r * H_ + y) * 64;
        arp = ar + ((size_t)r * H_ + y) * 64;
    }
    #pragma unroll
    for (int ct = 0; ct < 4; ++ct) {
        int col = col0 + ct * 16 + lrow;
        if (col >= Nc) continue;
        float wa = 0.f, wb = 0.f;
        if constexpr (FUSE) { wa = alp[ct * 16 + lrow]; wb = arp[ct * 16 + lrow]; }
        #pragma unroll
        for (int g = 0; g < 4; ++g) {
            int row = rbase + g;
            half_t zh = (half_t)acc[ct][g];
            if (row < N_) Zr[(size_t)row * Nc + col] = zh;
            if constexpr (FUSE) {
                float zf = (float)zh;
                elv[g] = fmaf(zf, wa, elv[g]);
                erv[g] = fmaf(zf, wb, erv[g]);
            }
        }
    }
    if constexpr (FUSE) {
        #pragma unroll
        for (int g = 0; g < 4; ++g) {
            #pragma unroll
            for (int m = 1; m < 16; m <<= 1) {
                elv[g] += __shfl_xor(elv[g], m);
                erv[g] += __shfl_xor(erv[g], m);
            }
        }
        if (lrow == 0) {
            #pragma unroll
            for (int g = 0; g < 4; ++g) {
                int row = rbase + g;
                if (row < N_) {
                    size_t o = ((size_t)r * N_ + row) * H_ + y;
                    el[o] = elv[g] * LOG2E;
                    er[o] = erv[g] * LOG2E;
                }
            }
        }
    }
}

// ---------------- attention logits (layer 2 only) ----------------
template <int Dd>
__global__ __launch_bounds__(256) void attn2_kernel(
        const half_t* __restrict__ z, const float* __restrict__ al,
        const float* __restrict__ ar, float* __restrict__ el,
        float* __restrict__ er) {
    int t = blockIdx.x * 256 + threadIdx.x;
    if (t >= R_ * N_ * H_) return;
    int rn = t / H_, h = t - rn * H_;
    int r = rn / N_;
    const half_t* zrow = z + (size_t)rn * (3 * Dd) + h * Dd;
    const float* alp = al + (r * H_ + h) * Dd;
    const float* arp = ar + (r * H_ + h) * Dd;
    float p0 = 0.f, p1 = 0.f, q0 = 0.f, q1 = 0.f;
    #pragma unroll
    for (int c = 0; c < Dd / 8; ++c) {
        f16x8 zv = *(const f16x8*)(zrow + c * 8);
        #pragma unroll
        for (int j = 0; j < 8; j += 2) {
            float za = (float)zv[j], zb = (float)zv[j + 1];
            p0 += za * alp[c * 8 + j];
            p1 += zb * alp[c * 8 + j + 1];
            q0 += za * arp[c * 8 + j];
            q1 += zb * arp[c * 8 + j + 1];
        }
    }
    el[t] = (p0 + p1) * LOG2E;
    er[t] = (q0 + q1) * LOG2E;
}

// ---------------- split-relation softmax-aggregate (v18) ----------------
// v17 structure (one wave per (node, relation): ceil(deg_r/4) iterations =
// 85% slot efficiency vs merged agg14's 62%) with the R6 traffic bug fixed:
// the 'act' exec-mask guard is RESTORED on the z gathers. R6 measured the
// cost of dropping it: dead sub-lanes (sub >= LPE) loaded a 4th 128B line
// per edge -> FETCH_SIZE 268->378MB (+41%), 89.5->116.9us. Masked lanes
// gate bytes, not just correctness.
template <int Dd, int VEC, bool RELU, typename OutT, bool TILED>
__global__ __launch_bounds__(384) void agg18_kernel(
        const int* __restrict__ rowptr, const int* __restrict__ csr_src,
        const half_t* __restrict__ z, const float* __restrict__ el,
        const float* __restrict__ er, const float* __restrict__ bias,
        OutT* __restrict__ out, float scale) {
    constexpr int ROWH = 3 * Dd;        // halves per z row
    constexpr int LPE  = ROWH / VEC;    // sub-lanes per edge (24 / 30)
    constexpr int PH   = Dd / VEC;      // sub-lanes per head (8 / 10)
    using fv = typename vecT<VEC>::type;
    int lane = threadIdx.x;             // 0..63
    int r    = threadIdx.y;             // relation 0..2
    int slot = threadIdx.z;             // node slot 0..1
    int n = blockIdx.x * 2 + slot;
    int hf = lane >> 5;                 // half-wave index
    int sub = lane & 31;
    bool act = sub < LPE;
    int hl = act ? sub / PH : 0;
    int dl = act ? sub - hl * PH : 0;
    int zoff = VEC * sub;
    int ii = rowptr[r * (N_ + 1) + n];
    int ee = rowptr[r * (N_ + 1) + n + 1];
    float erv = er[((size_t)r * N_ + n) * H_ + hl];
    const int* cs = csr_src + (size_t)r * E_;
    const half_t* zr = z + (size_t)r * N_ * ROWH;
    const float* elr = el + (size_t)r * N_ * H_;
    fv ah = {};                         // fp16 packed accumulator
    float ll = 0.f;
    for (; ii < ee; ii += 4) {          // wave-uniform trip count
        int eA = ii + hf, eB = ii + 2 + hf;
        bool okA = eA < ee, okB = eB < ee;
        int sA = cs[eA];                // s3 = src*3 (overread-safe)
        int sB = cs[eB];
        float xA = elr[sA + hl] + erv;
        float xB = elr[sB + hl] + erv;
        fv zA = {}, zB = {};
        if (act) {                      // exec-masked: dead lanes fetch 0 bytes
            zA = *(const fv*)(zr + (size_t)sA * Dd + zoff);
            zB = *(const fv*)(zr + (size_t)sB * Dd + zoff);
        }
        xA = fmaxf(xA, NEG_SLOPE * xA);
        xB = fmaxf(xB, NEG_SLOPE * xB);
        float cA = okA ? __builtin_amdgcn_exp2f(xA) : 0.f;
        float cB = okB ? __builtin_amdgcn_exp2f(xB) : 0.f;
        ll += cA + cB;
        half_t hA = (half_t)cA, hB = (half_t)cB;
        fv vA, vB;
        #pragma unroll
        for (int v = 0; v < VEC; ++v) { vA[v] = hA; vB[v] = hB; }
        ah += vA * zA + vB * zB;        // v_pk_fma_f16
    }
    // ---- per-relation epilogue (same math as agg14, single r) ----
    float aa[VEC];
    #pragma unroll
    for (int v = 0; v < VEC; ++v) aa[v] = (float)ah[v];
    #pragma unroll
    for (int v = 0; v < VEC; ++v) aa[v] += __shfl(aa[v], lane ^ 32);
    ll += __shfl(ll, lane ^ 32);
    float li = (ll > 0.f) ? 1.f / ll : 0.f;
    const float* br = bias + r * ROWH + hl * Dd + VEC * dl;
    float vacc[VEC];
    #pragma unroll
    for (int v = 0; v < VEC; ++v) {
        float t = aa[v] * li + br[v];
        if (RELU) t = fmaxf(t, 0.f);
        vacc[v] = t;
    }
    int base = lane & 32;
    int p1 = sub + PH;     if (p1 >= LPE) p1 -= LPE;
    int p2 = sub + 2 * PH; if (p2 >= LPE) p2 -= LPE;
    #pragma unroll
    for (int v = 0; v < VEC; ++v)
        vacc[v] += __shfl(vacc[v], base + p1) + __shfl(vacc[v], base + p2);
    int srcl = lane / VEC;
    int cm = lane & (VEC - 1);
    float tv[VEC];
    #pragma unroll
    for (int v = 0; v < VEC; ++v) tv[v] = __shfl(vacc[v], srcl);
    float outv = tv[0];
    #pragma unroll
    for (int v = 1; v < VEC; ++v) outv = (cm == v) ? tv[v] : outv;
    // ---- cross-relation sum via LDS ----
    __shared__ float red[2][3][64];
    red[slot][r][lane] = outv;
    __syncthreads();
    if (r == 0) {
        float o = (red[slot][0][lane] + red[slot][1][lane] + red[slot][2][lane]) * scale;
        if constexpr (TILED) {
            // lane == k (0..63); write fragment-tiled A' for next layer (KB=2)
            int rowtile = n >> 4;
            int kb = lane >> 5;
            int fl = (n & 15) + ((lane >> 3) & 3) * 16;
            int elo = lane & 7;
            size_t ho = (((size_t)rowtile * 2 + kb) * 64 + fl) * 8 + elo;
            ((half_t*)out)[ho] = (half_t)o;
        } else {
            if (lane < Dd) out[(size_t)n * Dd + lane] = (OutT)o;
        }
    }
}

// ---------------- launch ----------------
static inline size_t align256(size_t x) { return (x + 255) & ~(size_t)255; }

extern "C" void kernel_launch(void* const* d_in, const int* in_sizes, int n_in,
                              void* d_out, int out_size, void* d_ws, size_t ws_size,
                              hipStream_t stream) {
    const float* feat = (const float*)d_in[0];
    const int*   src  = (const int*)d_in[1];
    const int*   dst  = (const int*)d_in[2];
    const float* W1   = (const float*)d_in[3];
    const float* al1  = (const float*)d_in[4];
    const float* ar1  = (const float*)d_in[5];
    const float* b1   = (const float*)d_in[6];
    const float* W2   = (const float*)d_in[7];
    const float* al2  = (const float*)d_in[8];
    const float* ar2  = (const float*)d_in[9];
    const float* b2   = (const float*)d_in[10];
    float* out = (float*)d_out;

    // workspace carve
    char* ws = (char*)d_ws;
    size_t off = 0;
    half_t* zbuf  = (half_t*)(ws + off); off += align256((size_t)R_ * N_ * (3 * HID_) * 2);
    half_t* featT = (half_t*)(ws + off); off += align256((size_t)NRT * 4 * 64 * 8 * 2);
    half_t* h1T   = (half_t*)(ws + off); off += align256((size_t)NRT * 2 * 64 * 8 * 2);
    half_t* B1f   = (half_t*)(ws + off); off += align256((size_t)R_ * 3 * 4 * 4 * 64 * 8 * 2);
    half_t* B2f   = (half_t*)(ws + off); off += align256((size_t)R_ * 2 * 2 * 4 * 64 * 8 * 2);
    float* el   = (float*)(ws + off); off += align256((size_t)R_ * N_ * H_ * 4);
    float* er   = (float*)(ws + off); off += align256((size_t)R_ * N_ * H_ * 4);
    int* deg    = (int*)(ws + off);   off += align256((size_t)R_ * N_ * 4);
    int* rowptr = (int*)(ws + off);   off += align256((size_t)R_ * (N_ + 1) * 4);
    int* cursor = (int*)(ws + off);   off += align256((size_t)R_ * N_ * 4);
    int* bsum   = (int*)(ws + off);   off += align256((size_t)R_ * NCH2 * 4);
    int* csr    = (int*)(ws + off);   off += align256((size_t)R_ * E_ * 4 + 64);
    (void)ws_size; (void)n_in; (void)in_sizes; (void)out_size;

    const int ROW_TILES = (N_ + 63) / 64;              // 782
    const int ATTN_BLOCKS = (R_ * N_ * H_ + 255) / 256;// 1758
    const int E4_BLOCKS = (R_ * E_ / 4 + 255) / 256;   // 1172
    const int PREP_BLOCKS = 3189 + E4_BLOCKS;          // 4361
    const dim3 AGG_BLK(64, 3, 2);                      // 2 nodes x 3 relations
    const int AGG_GRID = N_ / 2;                       // 25000

    // ---- deg zero (stream-ordered, graph-capturable) then merged prep+hist ----
    hipMemsetAsync(deg, 0, (size_t)R_ * N_ * 4, stream);
    prep_kernel<<<PREP_BLOCKS, 256, 0, stream>>>(feat, featT, W1, B1f, W2, B2f,
                                                 h1T, csr, dst, deg);

    // ---- CSR build (shared by both layers) ----
    scanA_kernel<<<dim3(NCH, R_), 256, 0, stream>>>(deg, bsum);
    scanC_kernel<<<dim3(NCH, R_), 256, 0, stream>>>(deg, bsum, rowptr, cursor);
    fill_kernel<<<E4_BLOCKS, 256, 0, stream>>>(src, dst, cursor, csr);

    // ---- layer 1: IN -> H*HID, relu; gemm fuses el/er; agg writes h1T tiled ----
    mfma_gemm3_kernel<IN_, 3, true><<<dim3(ROW_TILES, 3, R_), 256, 0, stream>>>(
        featT, B1f, zbuf, H_ * HID_, al1, ar1, el, er);
    agg18_kernel<HID_, 8, true, half_t, true><<<AGG_GRID, AGG_BLK, 0, stream>>>(
        rowptr, csr, zbuf, el, er, b1, h1T, 1.f / (H_ * R_));

    // ---- layer 2: HID -> H*C, no relu; agg writes d_out (fp32) ----
    mfma_gemm3_kernel<HID_, 2, false><<<dim3(ROW_TILES, 2, R_), 256, 0, stream>>>(
        h1T, B2f, zbuf, H_ * C_, nullptr, nullptr, nullptr, nullptr);
    attn2_kernel<C_><<<ATTN_BLOCKS, 256, 0, stream>>>(zbuf, al2, ar2, el, er);
    agg18_kernel<C_, 4, false, float, false><<<AGG_GRID, AGG_BLK, 0, stream>>>(
        rowptr, csr, zbuf, el, er, b2, out, 1.f / (H_ * R_));
}

// Round 8
// 436.077 us; speedup vs baseline: 1.1298x; 1.1056x over previous
//
#include <hip/hip_runtime.h>

// Problem constants (fixed by reference)
#define R_   3
#define N_   50000
#define E_   400000
#define IN_  128
#define HID_ 64
#define C_   40
#define H_   3
#define NEG_SLOPE 0.2f
#define LOG2E 1.4426950408889634f

#define SCAN_CHUNK 1024
#define NCH  49      // ceil(N_/1024)
#define NCH2 64      // padded stride

#define MPAD 50048   // 782*64 rows (grid-rounded)
#define NRT  3128    // MPAD/16 fragment row-tiles

typedef _Float16 half_t;
typedef _Float16 f16x8 __attribute__((ext_vector_type(8)));
typedef _Float16 f16x4 __attribute__((ext_vector_type(4)));
typedef float float4v __attribute__((ext_vector_type(4)));

template <int V> struct vecT;
template <> struct vecT<4> { typedef f16x4 type; };
template <> struct vecT<8> { typedef f16x8 type; };

// ---------------- merged prep kernel (includes hist) ----------------
// block ranges:
//   [0, 3128)       cast_tiled: feat fp32 -> fragment-tiled fp16 A'
//   [3128, 3164)    bprep<128,3>: W1 -> B1f
//   [3164, 3176)    bprep<64,2>:  W2 -> B2f
//   [3176, 3188)    zero h1T pad row-tiles (3072 halves)
//   [3188, 4360)    hist: deg atomics (deg pre-zeroed via hipMemsetAsync)

template <int K, int NY>
__device__ inline void bprep_body(int idx, const float* __restrict__ W,
                                  half_t* __restrict__ Bf, int Nc) {
    constexpr int KB = K / 32;
    const int TOT = R_ * NY * KB * 4 * 64;
    if (idx >= TOT) return;
    int lane = idx & 63;
    int ct = (idx >> 6) & 3;
    int t = idx >> 8;                 // (r*NY + y)*KB + kb
    int kb = t % KB; t /= KB;
    int y = t % NY;  int r = t / NY;
    int col = y * 64 + ct * 16 + (lane & 15);
    int k0 = kb * 32 + (lane >> 4) * 8;
    f16x8 h = {};
    if (col < Nc) {
        #pragma unroll
        for (int j = 0; j < 8; ++j)
            h[j] = (half_t)W[((size_t)r * K + k0 + j) * Nc + col];
    }
    ((f16x8*)Bf)[idx] = h;
}

__global__ void prep_kernel(const float* __restrict__ feat, half_t* __restrict__ At,
                            const float* __restrict__ W1, half_t* __restrict__ B1f,
                            const float* __restrict__ W2, half_t* __restrict__ B2f,
                            half_t* __restrict__ h1T,
                            const int* __restrict__ dst, int* __restrict__ deg) {
    int b = blockIdx.x;
    if (b < 3128) {
        int idx = b * 256 + threadIdx.x;
        int lane = idx & 63;
        int kb = (idx >> 6) & 3;
        int rowtile = idx >> 8;
        int row = rowtile * 16 + (lane & 15);
        int k = kb * 32 + (lane >> 4) * 8;
        f16x8 h = {};
        if (row < N_) {
            const float* p = feat + (size_t)row * IN_ + k;
            float4 a = ((const float4*)p)[0];
            float4 c = ((const float4*)p)[1];
            h[0] = (half_t)a.x; h[1] = (half_t)a.y; h[2] = (half_t)a.z; h[3] = (half_t)a.w;
            h[4] = (half_t)c.x; h[5] = (half_t)c.y; h[6] = (half_t)c.z; h[7] = (half_t)c.w;
        }
        ((f16x8*)At)[idx] = h;
    } else if (b < 3164) {
        bprep_body<IN_, 3>((b - 3128) * 256 + threadIdx.x, W1, B1f, H_ * HID_);
    } else if (b < 3176) {
        bprep_body<HID_, 2>((b - 3164) * 256 + threadIdx.x, W2, B2f, H_ * C_);
    } else if (b < 3188) {
        int i = (b - 3176) * 256 + threadIdx.x;
        if (i < 3072) h1T[(size_t)3125 * 2 * 512 + i] = (half_t)0.f;
    } else {
        // hist: 4 edges per thread -> 4 independent atomic chains in flight
        const int T = (R_ * E_) / 4;
        int t = (b - 3188) * 256 + threadIdx.x;
        if (t < T) {
            #pragma unroll
            for (int j = 0; j < 4; ++j) {
                int idx = t + j * T;
                int r = idx / E_;
                atomicAdd(&deg[r * N_ + dst[idx]], 1);
            }
        }
    }
}

// ---------------- CSR build ----------------
__global__ void scanA_kernel(const int* __restrict__ deg, int* __restrict__ bsum) {
    int r = blockIdx.y, ch = blockIdx.x, tid = threadIdx.x;
    int base = ch * SCAN_CHUNK + tid * 4;
    int s = 0;
    for (int j = 0; j < 4; ++j) {
        int i = base + j;
        if (i < N_) s += deg[r * N_ + i];
    }
    __shared__ int red[256];
    red[tid] = s; __syncthreads();
    for (int off = 128; off; off >>= 1) {
        if (tid < off) red[tid] += red[tid + off];
        __syncthreads();
    }
    if (tid == 0) bsum[r * NCH2 + ch] = red[0];
}

// scanC: folds the 49-element chunk-prefix into each block (wave 0 re-scans).
__global__ void scanC_kernel(const int* __restrict__ deg, const int* __restrict__ bsum,
                             int* __restrict__ rowptr, int* __restrict__ cursor) {
    int r = blockIdx.y, ch = blockIdx.x, tid = threadIdx.x;
    __shared__ int chbase_s;
    if (tid < 64) {
        int v = (tid < NCH) ? bsum[r * NCH2 + tid] : 0;
        int s = v;
        #pragma unroll
        for (int off = 1; off < 64; off <<= 1) {
            int t = __shfl_up(s, off);
            if (tid >= off) s += t;
        }
        if (tid == ch) chbase_s = s - v;   // exclusive prefix of chunk ch
    }
    int base = ch * SCAN_CHUNK + tid * 4;
    int v[4]; int s = 0;
    for (int j = 0; j < 4; ++j) {
        int i = base + j;
        v[j] = (i < N_) ? deg[r * N_ + i] : 0;
        s += v[j];
    }
    __shared__ int buf[256];
    buf[tid] = s; __syncthreads();
    for (int off = 1; off < 256; off <<= 1) {
        int t2 = (tid >= off) ? buf[tid - off] : 0;
        __syncthreads();
        buf[tid] += t2;
        __syncthreads();
    }
    int excl = buf[tid] - s + chbase_s;
    int run = excl;
    for (int j = 0; j < 4; ++j) {
        int i = base + j;
        if (i < N_) {
            rowptr[r * (N_ + 1) + i] = run;
            cursor[r * N_ + i] = run;
            run += v[j];
        }
    }
    if (ch == 0 && tid == 0) rowptr[r * (N_ + 1) + N_] = E_;
}

// ---------------- MFMA GEMM v3 body: fragment-ordered operands ----------------
template <int K, int NY, bool FUSE>
__device__ __forceinline__ void gemm3_body(
        int bx, int y, int r, int tid,
        const half_t* __restrict__ At, const half_t* __restrict__ Bf,
        half_t* __restrict__ Z, int Nc,
        const float* __restrict__ al, const float* __restrict__ ar,
        float* __restrict__ el, float* __restrict__ er) {
    constexpr int KB = K / 32;
    int wave = tid >> 6, lane = tid & 63;
    int rowtile = bx * 4 + wave;
    const f16x8* Ap = (const f16x8*)At + (size_t)rowtile * KB * 64 + lane;
    const f16x8* Bp = (const f16x8*)Bf + (size_t)(r * NY + y) * KB * 4 * 64 + lane;
    float4v acc[4] = {};
    #pragma unroll
    for (int kb = 0; kb < KB; ++kb) {
        f16x8 af = Ap[kb * 64];
        #pragma unroll
        for (int ct = 0; ct < 4; ++ct) {
            f16x8 bf = Bp[(kb * 4 + ct) * 64];
            acc[ct] = __builtin_amdgcn_mfma_f32_16x16x32_f16(af, bf, acc[ct], 0, 0, 0);
        }
    }
    int lrow = lane & 15, lq = lane >> 4;
    half_t* Zr = Z + (size_t)r * N_ * Nc;
    int rbase = rowtile * 16 + lq * 4;
    int col0 = y * 64;
    float elv[4] = {}, erv[4] = {};
    const float* alp;
    const float* arp;
    if constexpr (FUSE) {
        alp = al + ((size_t)r * H_ + y) * 64;
        arp = ar + ((size_t)r * H_ + y) * 64;
    }
    #pragma unroll
    for (int ct = 0; ct < 4; ++ct) {
        int col = col0 + ct * 16 + lrow;
        if (col >= Nc) continue;
        float wa = 0.f, wb = 0.f;
        if constexpr (FUSE) { wa = alp[ct * 16 + lrow]; wb = arp[ct * 16 + lrow]; }
        #pragma unroll
        for (int g = 0; g < 4; ++g) {
            int row = rbase + g;
            half_t zh = (half_t)acc[ct][g];
            if (row < N_) Zr[(size_t)row * Nc + col] = zh;
            if constexpr (FUSE) {
                float zf = (float)zh;
                elv[g] = fmaf(zf, wa, elv[g]);
                erv[g] = fmaf(zf, wb, erv[g]);
            }
        }
    }
    if constexpr (FUSE) {
        #pragma unroll
        for (int g = 0; g < 4; ++g) {
            #pragma unroll
            for (int m = 1; m < 16; m <<= 1) {
                elv[g] += __shfl_xor(elv[g], m);
                erv[g] += __shfl_xor(erv[g], m);
            }
        }
        if (lrow == 0) {
            #pragma unroll
            for (int g = 0; g < 4; ++g) {
                int row = rbase + g;
                if (row < N_) {
                    size_t o = ((size_t)r * N_ + row) * H_ + y;
                    el[o] = elv[g] * LOG2E;
                    er[o] = erv[g] * LOG2E;
                }
            }
        }
    }
}

// standalone GEMM kernel (layer 2)
template <int K, int NY, bool FUSE>
__global__ __launch_bounds__(256) void mfma_gemm3_kernel(
        const half_t* __restrict__ At, const half_t* __restrict__ Bf,
        half_t* __restrict__ Z, int Nc,
        const float* __restrict__ al, const float* __restrict__ ar,
        float* __restrict__ el, float* __restrict__ er) {
    gemm3_body<K, NY, FUSE>(blockIdx.x, blockIdx.y, blockIdx.z, threadIdx.x,
                            At, Bf, Z, Nc, al, ar, el, er);
}

// ---------------- merged fill + GEMM L1 ----------------
// fill (blocks [0, FB)) is pure-latency (R2: VALUBusy 0.6%, HBM 10%, all
// pipes idle on ~800cy atomic round-trips); gemm-L1 (blocks [FB, FB+7038))
// is MFMA/BW-bound. No dependency between them (fill needs scanC, gemm
// needs prep) -> one launch, complementary pipes co-resident per CU:
// combined time ~ max instead of sum.
#define FILL_BLOCKS 1172
template <int K, int NY, bool FUSE>
__global__ __launch_bounds__(256) void fillgemm_kernel(
        const int* __restrict__ src, const int* __restrict__ dst,
        int* __restrict__ cursor, int* __restrict__ csr_src,
        const half_t* __restrict__ At, const half_t* __restrict__ Bf,
        half_t* __restrict__ Z, int Nc,
        const float* __restrict__ al, const float* __restrict__ ar,
        float* __restrict__ el, float* __restrict__ er) {
    int b = blockIdx.x;
    if (b < FILL_BLOCKS) {
        // fill: store src*3; 4 edges/thread for atomic MLP
        const int T = (R_ * E_) / 4;
        int t = b * 256 + threadIdx.x;
        if (t >= T) return;
        int pos[4], s3[4], rr[4];
        #pragma unroll
        for (int j = 0; j < 4; ++j) {
            int idx = t + j * T;
            rr[j] = idx / E_;
            pos[j] = atomicAdd(&cursor[rr[j] * N_ + dst[idx]], 1);
            s3[j] = src[idx] * 3;
        }
        #pragma unroll
        for (int j = 0; j < 4; ++j)
            csr_src[(size_t)rr[j] * E_ + pos[j]] = s3[j];
    } else {
        int g = b - FILL_BLOCKS;
        int bx = g % 782;
        int rest = g / 782;
        int y = rest % NY;
        int r = rest / NY;
        gemm3_body<K, NY, FUSE>(bx, y, r, threadIdx.x, At, Bf, Z, Nc, al, ar, el, er);
    }
}

// ---------------- attention logits (layer 2 only) ----------------
template <int Dd>
__global__ __launch_bounds__(256) void attn2_kernel(
        const half_t* __restrict__ z, const float* __restrict__ al,
        const float* __restrict__ ar, float* __restrict__ el,
        float* __restrict__ er) {
    int t = blockIdx.x * 256 + threadIdx.x;
    if (t >= R_ * N_ * H_) return;
    int rn = t / H_, h = t - rn * H_;
    int r = rn / N_;
    const half_t* zrow = z + (size_t)rn * (3 * Dd) + h * Dd;
    const float* alp = al + (r * H_ + h) * Dd;
    const float* arp = ar + (r * H_ + h) * Dd;
    float p0 = 0.f, p1 = 0.f, q0 = 0.f, q1 = 0.f;
    #pragma unroll
    for (int c = 0; c < Dd / 8; ++c) {
        f16x8 zv = *(const f16x8*)(zrow + c * 8);
        #pragma unroll
        for (int j = 0; j < 8; j += 2) {
            float za = (float)zv[j], zb = (float)zv[j + 1];
            p0 += za * alp[c * 8 + j];
            p1 += zb * alp[c * 8 + j + 1];
            q0 += za * arp[c * 8 + j];
            q1 += zb * arp[c * 8 + j + 1];
        }
    }
    el[t] = (p0 + p1) * LOG2E;
    er[t] = (q0 + q1) * LOG2E;
}

// ---------------- fused softmax + gather + aggregate ----------------
// EXACT agg14 (measured 89.5us, VALU ~75%). Campaign log: R3 pipeline
// (106.9), R4 alpha-hoist (98.6), R6/R7 split-relation (116.9/111.5) all
// regressed it. Mechanism: the merged 3-relation loop keeps 12 independent
// gathers in flight per wave (3x the split version) — the relation
// interleave IS the latency hiding. Do not restructure this loop.
template <int Dd, int VEC, bool RELU, typename OutT, bool TILED>
__global__ __launch_bounds__(256) void agg14_kernel(
        const int* __restrict__ rowptr, const int* __restrict__ csr_src,
        const half_t* __restrict__ z, const float* __restrict__ el,
        const float* __restrict__ er, const float* __restrict__ bias,
        OutT* __restrict__ out, float scale) {
    constexpr int ROWH = 3 * Dd;        // halves per z row
    constexpr int LPE  = ROWH / VEC;    // sub-lanes per edge (24 / 30)
    constexpr int PH   = Dd / VEC;      // sub-lanes per head (8 / 10)
    using fv = typename vecT<VEC>::type;
    int n = blockIdx.x * 4 + (threadIdx.x >> 6);
    int lane = threadIdx.x & 63;
    if (n >= N_) return;
    int hf = lane >> 5;                 // half-wave index
    int sub = lane & 31;
    bool act = sub < LPE;
    int hl = act ? sub / PH : 0;
    int dl = act ? sub - hl * PH : 0;
    int zoff = VEC * sub;
    int ii[R_], ee[R_];
    float ervv[R_];
    #pragma unroll
    for (int r = 0; r < R_; ++r) {
        ii[r] = rowptr[r * (N_ + 1) + n];
        ee[r] = rowptr[r * (N_ + 1) + n + 1];
        ervv[r] = er[((size_t)r * N_ + n) * H_ + hl];
    }
    fv ah[R_] = {};                     // fp16 packed accumulators
    float ll[R_] = {};
    while (ii[0] < ee[0] || ii[1] < ee[1] || ii[2] < ee[2]) {
        fv zA[R_], zB[R_];
        float xA[R_], xB[R_];
        bool okA[R_], okB[R_];
        #pragma unroll
        for (int r = 0; r < R_; ++r) {
            const int* cs = csr_src + (size_t)r * E_;
            const half_t* zr = z + (size_t)r * N_ * ROWH;
            const float* elr = el + (size_t)r * N_ * H_;
            int eA = ii[r] + hf, eB = ii[r] + 2 + hf;
            okA[r] = eA < ee[r];
            okB[r] = eB < ee[r];
            int sA = cs[okA[r] ? eA : 0];       // s3 = src*3
            int sB = cs[okB[r] ? eB : 0];
            xA[r] = elr[sA + hl] + ervv[r];
            xB[r] = elr[sB + hl] + ervv[r];
            zA[r] = {}; zB[r] = {};
            if (act) {
                zA[r] = *(const fv*)(zr + (size_t)sA * Dd + zoff);
                zB[r] = *(const fv*)(zr + (size_t)sB * Dd + zoff);
            }
        }
        #pragma unroll
        for (int r = 0; r < R_; ++r) {
            float xa = xA[r]; xa = fmaxf(xa, NEG_SLOPE * xa);
            float xb = xB[r]; xb = fmaxf(xb, NEG_SLOPE * xb);
            float cA = okA[r] ? __builtin_amdgcn_exp2f(xa) : 0.f;
            float cB = okB[r] ? __builtin_amdgcn_exp2f(xb) : 0.f;
            ll[r] += cA + cB;
            half_t hA = (half_t)cA, hB = (half_t)cB;
            fv vA, vB;
            #pragma unroll
            for (int v = 0; v < VEC; ++v) { vA[v] = hA; vB[v] = hB; }
            ah[r] += vA * zA[r] + vB * zB[r];   // v_pk_fma_f16
        }
        #pragma unroll
        for (int r = 0; r < R_; ++r) ii[r] += 4;
    }
    // ---- epilogue: convert to fp32 once, then cross-half combines ----
    float aa[R_][VEC];
    #pragma unroll
    for (int r = 0; r < R_; ++r)
        #pragma unroll
        for (int v = 0; v < VEC; ++v) aa[r][v] = (float)ah[r][v];
    #pragma unroll
    for (int r = 0; r < R_; ++r) {
        #pragma unroll
        for (int v = 0; v < VEC; ++v) aa[r][v] += __shfl(aa[r][v], lane ^ 32);
        ll[r] += __shfl(ll[r], lane ^ 32);
    }
    float vacc[VEC] = {};
    #pragma unroll
    for (int r = 0; r < R_; ++r) {
        float li = (ll[r] > 0.f) ? 1.f / ll[r] : 0.f;
        const float* br = bias + r * ROWH + hl * Dd + VEC * dl;
        #pragma unroll
        for (int v = 0; v < VEC; ++v) {
            float t = aa[r][v] * li + br[v];
            if (RELU) t = fmaxf(t, 0.f);
            vacc[v] += t;
        }
    }
    int base = lane & 32;
    int p1 = sub + PH;     if (p1 >= LPE) p1 -= LPE;
    int p2 = sub + 2 * PH; if (p2 >= LPE) p2 -= LPE;
    #pragma unroll
    for (int v = 0; v < VEC; ++v)
        vacc[v] += __shfl(vacc[v], base + p1) + __shfl(vacc[v], base + p2);
    int srcl = lane / VEC;
    int cm = lane & (VEC - 1);
    float tv[VEC];
    #pragma unroll
    for (int v = 0; v < VEC; ++v) tv[v] = __shfl(vacc[v], srcl);
    float outv = tv[0];
    #pragma unroll
    for (int v = 1; v < VEC; ++v) outv = (cm == v) ? tv[v] : outv;
    if constexpr (TILED) {
        // lane == k (0..63); write fragment-tiled A' for next layer (KB=2)
        int rowtile = n >> 4;
        int kb = lane >> 5;
        int fl = (n & 15) + ((lane >> 3) & 3) * 16;
        int elo = lane & 7;
        size_t ho = (((size_t)rowtile * 2 + kb) * 64 + fl) * 8 + elo;
        ((half_t*)out)[ho] = (half_t)(outv * scale);
    } else {
        if (lane < Dd) out[(size_t)n * Dd + lane] = (OutT)(outv * scale);
    }
}

// ---------------- launch ----------------
static inline size_t align256(size_t x) { return (x + 255) & ~(size_t)255; }

extern "C" void kernel_launch(void* const* d_in, const int* in_sizes, int n_in,
                              void* d_out, int out_size, void* d_ws, size_t ws_size,
                              hipStream_t stream) {
    const float* feat = (const float*)d_in[0];
    const int*   src  = (const int*)d_in[1];
    const int*   dst  = (const int*)d_in[2];
    const float* W1   = (const float*)d_in[3];
    const float* al1  = (const float*)d_in[4];
    const float* ar1  = (const float*)d_in[5];
    const float* b1   = (const float*)d_in[6];
    const float* W2   = (const float*)d_in[7];
    const float* al2  = (const float*)d_in[8];
    const float* ar2  = (const float*)d_in[9];
    const float* b2   = (const float*)d_in[10];
    float* out = (float*)d_out;

    // workspace carve
    char* ws = (char*)d_ws;
    size_t off = 0;
    half_t* zbuf  = (half_t*)(ws + off); off += align256((size_t)R_ * N_ * (3 * HID_) * 2);
    half_t* featT = (half_t*)(ws + off); off += align256((size_t)NRT * 4 * 64 * 8 * 2);
    half_t* h1T   = (half_t*)(ws + off); off += align256((size_t)NRT * 2 * 64 * 8 * 2);
    half_t* B1f   = (half_t*)(ws + off); off += align256((size_t)R_ * 3 * 4 * 4 * 64 * 8 * 2);
    half_t* B2f   = (half_t*)(ws + off); off += align256((size_t)R_ * 2 * 2 * 4 * 64 * 8 * 2);
    float* el   = (float*)(ws + off); off += align256((size_t)R_ * N_ * H_ * 4);
    float* er   = (float*)(ws + off); off += align256((size_t)R_ * N_ * H_ * 4);
    int* deg    = (int*)(ws + off);   off += align256((size_t)R_ * N_ * 4);
    int* rowptr = (int*)(ws + off);   off += align256((size_t)R_ * (N_ + 1) * 4);
    int* cursor = (int*)(ws + off);   off += align256((size_t)R_ * N_ * 4);
    int* bsum   = (int*)(ws + off);   off += align256((size_t)R_ * NCH2 * 4);
    int* csr    = (int*)(ws + off);   off += align256((size_t)R_ * E_ * 4);
    (void)ws_size; (void)n_in; (void)in_sizes; (void)out_size;

    const int ROW_TILES = (N_ + 63) / 64;              // 782
    const int NODE_WAVES = (N_ + 3) / 4;               // 12500
    const int ATTN_BLOCKS = (R_ * N_ * H_ + 255) / 256;// 1758
    const int E4_BLOCKS = (R_ * E_ / 4 + 255) / 256;   // 1172
    const int PREP_BLOCKS = 3188 + E4_BLOCKS;          // 4360
    const int FG_BLOCKS = FILL_BLOCKS + ROW_TILES * 3 * R_;  // 1172 + 7038

    // ---- deg zero (stream-ordered, graph-capturable) then merged prep+hist ----
    hipMemsetAsync(deg, 0, (size_t)R_ * N_ * 4, stream);
    prep_kernel<<<PREP_BLOCKS, 256, 0, stream>>>(feat, featT, W1, B1f, W2, B2f,
                                                 h1T, dst, deg);

    // ---- CSR scans ----
    scanA_kernel<<<dim3(NCH, R_), 256, 0, stream>>>(deg, bsum);
    scanC_kernel<<<dim3(NCH, R_), 256, 0, stream>>>(deg, bsum, rowptr, cursor);

    // ---- merged fill + gemm L1 (independent; complementary pipes) ----
    fillgemm_kernel<IN_, 3, true><<<FG_BLOCKS, 256, 0, stream>>>(
        src, dst, cursor, csr, featT, B1f, zbuf, H_ * HID_, al1, ar1, el, er);

    // ---- layer 1 aggregate: writes h1T (fragment-tiled fp16) ----
    agg14_kernel<HID_, 8, true, half_t, true><<<NODE_WAVES, 256, 0, stream>>>(
        rowptr, csr, zbuf, el, er, b1, h1T, 1.f / (H_ * R_));

    // ---- layer 2: HID -> H*C, no relu; agg writes d_out (fp32) ----
    mfma_gemm3_kernel<HID_, 2, false><<<dim3(ROW_TILES, 2, R_), 256, 0, stream>>>(
        h1T, B2f, zbuf, H_ * C_, nullptr, nullptr, nullptr, nullptr);
    attn2_kernel<C_><<<ATTN_BLOCKS, 256, 0, stream>>>(zbuf, al2, ar2, el, er);
    agg14_kernel<C_, 4, false, float, false><<<NODE_WAVES, 256, 0, stream>>>(
        rowptr, csr, zbuf, el, er, b2, out, 1.f / (H_ * R_));
}

// Round 9
// 390.630 us; speedup vs baseline: 1.2612x; 1.1163x over previous
//
#include <hip/hip_runtime.h>

// Problem constants (fixed by reference)
#define R_   3
#define N_   50000
#define E_   400000
#define IN_  128
#define HID_ 64
#define C_   40
#define H_   3
#define NEG_SLOPE 0.2f
#define LOG2E 1.4426950408889634f

#define MPAD 50048   // 782*64 rows (grid-rounded)
#define NRT  3128    // MPAD/16 fragment row-tiles
#define BCAP 32      // CSR bucket capacity: 128B = 1 cache line; max deg ~24

typedef _Float16 half_t;
typedef _Float16 f16x8 __attribute__((ext_vector_type(8)));
typedef _Float16 f16x4 __attribute__((ext_vector_type(4)));
typedef float float4v __attribute__((ext_vector_type(4)));

template <int V> struct vecT;
template <> struct vecT<4> { typedef f16x4 type; };
template <> struct vecT<8> { typedef f16x8 type; };

// ---------------- merged prep kernel ----------------
// Bucket CSR (cnt + fixed 32-slot buckets) replaces hist/scanA/scanC: the
// packed-CSR machinery (1.2M hist atomics + 2 scan kernels + 2 gaps) bought
// nothing the bucket doesn't give. prep is now pure streaming.
// block ranges:
//   [0, 3128)       cast_tiled: feat fp32 -> fragment-tiled fp16 A'
//   [3128, 3164)    bprep<128,3,4,64>: W1 -> B1f
//   [3164, 3178)    bprep<64,3,3,40>:  W2 -> B2f (40-col head tiles, padded)
//   [3178, 3190)    zero h1T pad row-tiles (3072 halves)
//   [3190, 3776)    zero bucket slot 0 (safe clamp target for empty rows)

template <int K, int NY, int CT, int TCOLS>
__device__ inline void bprep_body(int idx, const float* __restrict__ W,
                                  half_t* __restrict__ Bf, int Nc) {
    constexpr int KB = K / 32;
    const int TOT = R_ * NY * KB * CT * 64;
    if (idx >= TOT) return;
    int lane = idx & 63;
    int rest = idx >> 6;
    int ct = rest % CT; rest /= CT;
    int kb = rest % KB; rest /= KB;
    int y = rest % NY;  int r = rest / NY;
    int cw = ct * 16 + (lane & 15);
    int col = y * TCOLS + cw;
    int k0 = kb * 32 + (lane >> 4) * 8;
    f16x8 h = {};
    if (cw < TCOLS && col < Nc) {
        #pragma unroll
        for (int j = 0; j < 8; ++j)
            h[j] = (half_t)W[((size_t)r * K + k0 + j) * Nc + col];
    }
    ((f16x8*)Bf)[idx] = h;
}

__global__ void prep_kernel(const float* __restrict__ feat, half_t* __restrict__ At,
                            const float* __restrict__ W1, half_t* __restrict__ B1f,
                            const float* __restrict__ W2, half_t* __restrict__ B2f,
                            half_t* __restrict__ h1T, int* __restrict__ csr) {
    int b = blockIdx.x;
    if (b < 3128) {
        int idx = b * 256 + threadIdx.x;
        int lane = idx & 63;
        int kb = (idx >> 6) & 3;
        int rowtile = idx >> 8;
        int row = rowtile * 16 + (lane & 15);
        int k = kb * 32 + (lane >> 4) * 8;
        f16x8 h = {};
        if (row < N_) {
            const float* p = feat + (size_t)row * IN_ + k;
            float4 a = ((const float4*)p)[0];
            float4 c = ((const float4*)p)[1];
            h[0] = (half_t)a.x; h[1] = (half_t)a.y; h[2] = (half_t)a.z; h[3] = (half_t)a.w;
            h[4] = (half_t)c.x; h[5] = (half_t)c.y; h[6] = (half_t)c.z; h[7] = (half_t)c.w;
        }
        ((f16x8*)At)[idx] = h;
    } else if (b < 3164) {
        bprep_body<IN_, 3, 4, 64>((b - 3128) * 256 + threadIdx.x, W1, B1f, H_ * HID_);
    } else if (b < 3178) {
        bprep_body<HID_, 3, 3, 40>((b - 3164) * 256 + threadIdx.x, W2, B2f, H_ * C_);
    } else if (b < 3190) {
        int i = (b - 3178) * 256 + threadIdx.x;
        if (i < 3072) h1T[(size_t)3125 * 2 * 512 + i] = (half_t)0.f;
    } else {
        int rn = (b - 3190) * 256 + threadIdx.x;
        if (rn < R_ * N_) csr[(size_t)rn * BCAP] = 0;
    }
}

// ---------------- MFMA GEMM body: fragment-ordered operands ----------------
// Generalized over (CT groups, TCOLS per y-tile) so layer 2 can use 40-col
// head tiles and fuse el/er exactly like layer 1 (kills the attn2 pass).
template <int K, int NY, int CT, int TCOLS, bool FUSE>
__device__ __forceinline__ void gemm3_body(
        int bx, int y, int r, int tid,
        const half_t* __restrict__ At, const half_t* __restrict__ Bf,
        half_t* __restrict__ Z, int Nc,
        const float* __restrict__ al, const float* __restrict__ ar,
        float* __restrict__ el, float* __restrict__ er) {
    constexpr int KB = K / 32;
    int wave = tid >> 6, lane = tid & 63;
    int rowtile = bx * 4 + wave;
    const f16x8* Ap = (const f16x8*)At + (size_t)rowtile * KB * 64 + lane;
    const f16x8* Bp = (const f16x8*)Bf + (size_t)(r * NY + y) * KB * CT * 64 + lane;
    float4v acc[CT] = {};
    #pragma unroll
    for (int kb = 0; kb < KB; ++kb) {
        f16x8 af = Ap[kb * 64];
        #pragma unroll
        for (int ct = 0; ct < CT; ++ct) {
            f16x8 bf = Bp[(kb * CT + ct) * 64];
            acc[ct] = __builtin_amdgcn_mfma_f32_16x16x32_f16(af, bf, acc[ct], 0, 0, 0);
        }
    }
    int lrow = lane & 15, lq = lane >> 4;
    half_t* Zr = Z + (size_t)r * N_ * Nc;
    int rbase = rowtile * 16 + lq * 4;
    int col0 = y * TCOLS;
    float elv[4] = {}, erv[4] = {};
    const float* alp;
    const float* arp;
    if constexpr (FUSE) {
        alp = al + ((size_t)r * H_ + y) * TCOLS;
        arp = ar + ((size_t)r * H_ + y) * TCOLS;
    }
    #pragma unroll
    for (int ct = 0; ct < CT; ++ct) {
        int cw = ct * 16 + lrow;
        if (cw >= TCOLS) continue;       // padded cols (L2: 40..47)
        int col = col0 + cw;
        float wa = 0.f, wb = 0.f;
        if constexpr (FUSE) { wa = alp[cw]; wb = arp[cw]; }
        #pragma unroll
        for (int g = 0; g < 4; ++g) {
            int row = rbase + g;
            half_t zh = (half_t)acc[ct][g];
            if (row < N_) Zr[(size_t)row * Nc + col] = zh;
            if constexpr (FUSE) {
                float zf = (float)zh;
                elv[g] = fmaf(zf, wa, elv[g]);
                erv[g] = fmaf(zf, wb, erv[g]);
            }
        }
    }
    if constexpr (FUSE) {
        #pragma unroll
        for (int g = 0; g < 4; ++g) {
            #pragma unroll
            for (int m = 1; m < 16; m <<= 1) {
                elv[g] += __shfl_xor(elv[g], m);
                erv[g] += __shfl_xor(erv[g], m);
            }
        }
        if (lrow == 0) {
            #pragma unroll
            for (int g = 0; g < 4; ++g) {
                int row = rbase + g;
                if (row < N_) {
                    size_t o = ((size_t)r * N_ + row) * H_ + y;
                    el[o] = elv[g] * LOG2E;
                    er[o] = erv[g] * LOG2E;
                }
            }
        }
    }
}

// standalone GEMM kernel (layer 2, attn-fused via 40-col head tiles)
template <int K, int NY, int CT, int TCOLS, bool FUSE>
__global__ __launch_bounds__(256) void mfma_gemm3_kernel(
        const half_t* __restrict__ At, const half_t* __restrict__ Bf,
        half_t* __restrict__ Z, int Nc,
        const float* __restrict__ al, const float* __restrict__ ar,
        float* __restrict__ el, float* __restrict__ er) {
    gemm3_body<K, NY, CT, TCOLS, FUSE>(blockIdx.x, blockIdx.y, blockIdx.z,
                                       threadIdx.x, At, Bf, Z, Nc, al, ar, el, er);
}

// ---------------- merged fill + GEMM L1 ----------------
// fill (blocks [0,FB)): bucket scatter, 4 edges/thread for atomic MLP.
// ~153MB WRITE (64B-sector amplification of 4B scatters) + atomic RTs —
// intrinsic to counting-sort scatter. gemm-L1 backfills the same CUs.
#define FILL_BLOCKS 1172
template <int K, int NY, int CT, int TCOLS, bool FUSE>
__global__ __launch_bounds__(256) void fillgemm_kernel(
        const int* __restrict__ src, const int* __restrict__ dst,
        int* __restrict__ cnt, int* __restrict__ csr,
        const half_t* __restrict__ At, const half_t* __restrict__ Bf,
        half_t* __restrict__ Z, int Nc,
        const float* __restrict__ al, const float* __restrict__ ar,
        float* __restrict__ el, float* __restrict__ er) {
    int b = blockIdx.x;
    if (b < FILL_BLOCKS) {
        const int T = (R_ * E_) / 4;
        int t = b * 256 + threadIdx.x;
        if (t >= T) return;
        int pos[4], s3[4];
        size_t bo[4];
        #pragma unroll
        for (int j = 0; j < 4; ++j) {
            int idx = t + j * T;
            int r = idx / E_;
            int d = dst[idx];
            int rn = r * N_ + d;
            pos[j] = atomicAdd(&cnt[rn], 1);
            s3[j] = src[idx] * 3;
            bo[j] = (size_t)rn * BCAP;
        }
        #pragma unroll
        for (int j = 0; j < 4; ++j)
            if (pos[j] < BCAP) csr[bo[j] + pos[j]] = s3[j];
    } else {
        int g = b - FILL_BLOCKS;
        int bx = g % 782;
        int rest = g / 782;
        int y = rest % NY;
        int r = rest / NY;
        gemm3_body<K, NY, CT, TCOLS, FUSE>(bx, y, r, threadIdx.x,
                                           At, Bf, Z, Nc, al, ar, el, er);
    }
}

// ---------------- fused softmax + gather + aggregate (bucket CSR) ----------
// EXACT agg14 loop body (measured 89.5us; R3 pipeline / R4 hoist / R6-R7
// split all regressed it — the 3-relation interleave IS the latency hiding;
// do not restructure). Only the prologue changes: ii=0, ee=cnt[rn], per-node
// bucket base. Clamp target slot 0 is pre-zeroed for empty rows.
template <int Dd, int VEC, bool RELU, typename OutT, bool TILED>
__global__ __launch_bounds__(256) void agg19_kernel(
        const int* __restrict__ cnt, const int* __restrict__ csr,
        const half_t* __restrict__ z, const float* __restrict__ el,
        const float* __restrict__ er, const float* __restrict__ bias,
        OutT* __restrict__ out, float scale) {
    constexpr int ROWH = 3 * Dd;        // halves per z row
    constexpr int LPE  = ROWH / VEC;    // sub-lanes per edge (24 / 30)
    constexpr int PH   = Dd / VEC;      // sub-lanes per head (8 / 10)
    using fv = typename vecT<VEC>::type;
    int n = blockIdx.x * 4 + (threadIdx.x >> 6);
    int lane = threadIdx.x & 63;
    if (n >= N_) return;
    int hf = lane >> 5;                 // half-wave index
    int sub = lane & 31;
    bool act = sub < LPE;
    int hl = act ? sub / PH : 0;
    int dl = act ? sub - hl * PH : 0;
    int zoff = VEC * sub;
    int ii[R_], ee[R_];
    const int* csp[R_];
    float ervv[R_];
    #pragma unroll
    for (int r = 0; r < R_; ++r) {
        ii[r] = 0;
        ee[r] = cnt[r * N_ + n];
        csp[r] = csr + (size_t)(r * N_ + n) * BCAP;
        ervv[r] = er[((size_t)r * N_ + n) * H_ + hl];
    }
    fv ah[R_] = {};                     // fp16 packed accumulators
    float ll[R_] = {};
    while (ii[0] < ee[0] || ii[1] < ee[1] || ii[2] < ee[2]) {
        fv zA[R_], zB[R_];
        float xA[R_], xB[R_];
        bool okA[R_], okB[R_];
        #pragma unroll
        for (int r = 0; r < R_; ++r) {
            const half_t* zr = z + (size_t)r * N_ * ROWH;
            const float* elr = el + (size_t)r * N_ * H_;
            int eA = ii[r] + hf, eB = ii[r] + 2 + hf;
            okA[r] = eA < ee[r];
            okB[r] = eB < ee[r];
            int sA = csp[r][okA[r] ? eA : 0];   // s3 = src*3
            int sB = csp[r][okB[r] ? eB : 0];
            xA[r] = elr[sA + hl] + ervv[r];
            xB[r] = elr[sB + hl] + ervv[r];
            zA[r] = {}; zB[r] = {};
            if (act) {
                zA[r] = *(const fv*)(zr + (size_t)sA * Dd + zoff);
                zB[r] = *(const fv*)(zr + (size_t)sB * Dd + zoff);
            }
        }
        #pragma unroll
        for (int r = 0; r < R_; ++r) {
            float xa = xA[r]; xa = fmaxf(xa, NEG_SLOPE * xa);
            float xb = xB[r]; xb = fmaxf(xb, NEG_SLOPE * xb);
            float cA = okA[r] ? __builtin_amdgcn_exp2f(xa) : 0.f;
            float cB = okB[r] ? __builtin_amdgcn_exp2f(xb) : 0.f;
            ll[r] += cA + cB;
            half_t hA = (half_t)cA, hB = (half_t)cB;
            fv vA, vB;
            #pragma unroll
            for (int v = 0; v < VEC; ++v) { vA[v] = hA; vB[v] = hB; }
            ah[r] += vA * zA[r] + vB * zB[r];   // v_pk_fma_f16
        }
        #pragma unroll
        for (int r = 0; r < R_; ++r) ii[r] += 4;
    }
    // ---- epilogue: convert to fp32 once, then cross-half combines ----
    float aa[R_][VEC];
    #pragma unroll
    for (int r = 0; r < R_; ++r)
        #pragma unroll
        for (int v = 0; v < VEC; ++v) aa[r][v] = (float)ah[r][v];
    #pragma unroll
    for (int r = 0; r < R_; ++r) {
        #pragma unroll
        for (int v = 0; v < VEC; ++v) aa[r][v] += __shfl(aa[r][v], lane ^ 32);
        ll[r] += __shfl(ll[r], lane ^ 32);
    }
    float vacc[VEC] = {};
    #pragma unroll
    for (int r = 0; r < R_; ++r) {
        float li = (ll[r] > 0.f) ? 1.f / ll[r] : 0.f;
        const float* br = bias + r * ROWH + hl * Dd + VEC * dl;
        #pragma unroll
        for (int v = 0; v < VEC; ++v) {
            float t = aa[r][v] * li + br[v];
            if (RELU) t = fmaxf(t, 0.f);
            vacc[v] += t;
        }
    }
    int base = lane & 32;
    int p1 = sub + PH;     if (p1 >= LPE) p1 -= LPE;
    int p2 = sub + 2 * PH; if (p2 >= LPE) p2 -= LPE;
    #pragma unroll
    for (int v = 0; v < VEC; ++v)
        vacc[v] += __shfl(vacc[v], base + p1) + __shfl(vacc[v], base + p2);
    int srcl = lane / VEC;
    int cm = lane & (VEC - 1);
    float tv[VEC];
    #pragma unroll
    for (int v = 0; v < VEC; ++v) tv[v] = __shfl(vacc[v], srcl);
    float outv = tv[0];
    #pragma unroll
    for (int v = 1; v < VEC; ++v) outv = (cm == v) ? tv[v] : outv;
    if constexpr (TILED) {
        // lane == k (0..63); write fragment-tiled A' for next layer (KB=2)
        int rowtile = n >> 4;
        int kb = lane >> 5;
        int fl = (n & 15) + ((lane >> 3) & 3) * 16;
        int elo = lane & 7;
        size_t ho = (((size_t)rowtile * 2 + kb) * 64 + fl) * 8 + elo;
        ((half_t*)out)[ho] = (half_t)(outv * scale);
    } else {
        if (lane < Dd) out[(size_t)n * Dd + lane] = (OutT)(outv * scale);
    }
}

// ---------------- launch ----------------
static inline size_t align256(size_t x) { return (x + 255) & ~(size_t)255; }

extern "C" void kernel_launch(void* const* d_in, const int* in_sizes, int n_in,
                              void* d_out, int out_size, void* d_ws, size_t ws_size,
                              hipStream_t stream) {
    const float* feat = (const float*)d_in[0];
    const int*   src  = (const int*)d_in[1];
    const int*   dst  = (const int*)d_in[2];
    const float* W1   = (const float*)d_in[3];
    const float* al1  = (const float*)d_in[4];
    const float* ar1  = (const float*)d_in[5];
    const float* b1   = (const float*)d_in[6];
    const float* W2   = (const float*)d_in[7];
    const float* al2  = (const float*)d_in[8];
    const float* ar2  = (const float*)d_in[9];
    const float* b2   = (const float*)d_in[10];
    float* out = (float*)d_out;

    // workspace carve
    char* ws = (char*)d_ws;
    size_t off = 0;
    half_t* zbuf  = (half_t*)(ws + off); off += align256((size_t)R_ * N_ * (3 * HID_) * 2);
    half_t* featT = (half_t*)(ws + off); off += align256((size_t)NRT * 4 * 64 * 8 * 2);
    half_t* h1T   = (half_t*)(ws + off); off += align256((size_t)NRT * 2 * 64 * 8 * 2);
    half_t* B1f   = (half_t*)(ws + off); off += align256((size_t)R_ * 3 * 4 * 4 * 64 * 8 * 2);
    half_t* B2f   = (half_t*)(ws + off); off += align256((size_t)R_ * 3 * 2 * 3 * 64 * 8 * 2);
    float* el   = (float*)(ws + off); off += align256((size_t)R_ * N_ * H_ * 4);
    float* er   = (float*)(ws + off); off += align256((size_t)R_ * N_ * H_ * 4);
    int* cnt    = (int*)(ws + off);   off += align256((size_t)R_ * N_ * 4);
    int* csr    = (int*)(ws + off);   off += align256((size_t)R_ * N_ * BCAP * 4);
    (void)ws_size; (void)n_in; (void)in_sizes; (void)out_size;

    const int ROW_TILES = (N_ + 63) / 64;              // 782
    const int NODE_WAVES = (N_ + 3) / 4;               // 12500
    const int PREP_BLOCKS = 3776;
    const int FG_BLOCKS = FILL_BLOCKS + ROW_TILES * 3 * R_;  // 1172 + 7038

    // ---- cnt zero (stream-ordered, graph-capturable), then prep ----
    hipMemsetAsync(cnt, 0, (size_t)R_ * N_ * 4, stream);
    prep_kernel<<<PREP_BLOCKS, 256, 0, stream>>>(feat, featT, W1, B1f, W2, B2f,
                                                 h1T, csr);

    // ---- merged bucket-fill + gemm L1 (independent; complementary pipes) ----
    fillgemm_kernel<IN_, 3, 4, 64, true><<<FG_BLOCKS, 256, 0, stream>>>(
        src, dst, cnt, csr, featT, B1f, zbuf, H_ * HID_, al1, ar1, el, er);

    // ---- layer 1 aggregate: writes h1T (fragment-tiled fp16) ----
    agg19_kernel<HID_, 8, true, half_t, true><<<NODE_WAVES, 256, 0, stream>>>(
        cnt, csr, zbuf, el, er, b1, h1T, 1.f / (H_ * R_));

    // ---- layer 2: HID -> H*C via 40-col head tiles, attn fused ----
    mfma_gemm3_kernel<HID_, 3, 3, 40, true><<<dim3(ROW_TILES, 3, R_), 256, 0, stream>>>(
        h1T, B2f, zbuf, H_ * C_, al2, ar2, el, er);
    agg19_kernel<C_, 4, false, float, false><<<NODE_WAVES, 256, 0, stream>>>(
        cnt, csr, zbuf, el, er, b2, out, 1.f / (H_ * R_));
}